// Round 7
// baseline (599.107 us; speedup 1.0000x reference)
//
#include <hip/hip_runtime.h>
#include <hip/hip_bf16.h>
#include <stdint.h>

typedef __bf16 bf16x8 __attribute__((ext_vector_type(8)));
typedef float f32x4 __attribute__((ext_vector_type(4)));
typedef unsigned short ushort_t;
typedef ushort_t ushort4v __attribute__((ext_vector_type(4)));
typedef ushort_t ushort8v __attribute__((ext_vector_type(8)));
typedef float float4v __attribute__((ext_vector_type(4)));

#define D_MODEL 2048
#define NH 16
#define HD 128
#define B_ 4
#define T_ 2048
#define M_ (B_*T_)

__device__ __forceinline__ float b2f(ushort_t u){ union{uint32_t i; float f;} v; v.i=((uint32_t)u)<<16; return v.f; }
__device__ __forceinline__ ushort_t f2b(float f){ union{float f; uint32_t i;} v; v.f=f; uint32_t r = v.i + 0x7FFFu + ((v.i>>16)&1u); return (ushort_t)(r>>16); }
__device__ __forceinline__ float fexp2(float x){ return __builtin_amdgcn_exp2f(x); }

__device__ __forceinline__ void gload16(const void* g, void* l) {
  __builtin_amdgcn_global_load_lds((const __attribute__((address_space(1))) void*)g,
                                   (__attribute__((address_space(3))) void*)l, 16, 0, 0);
}

// ---------------- fp32 -> bf16 elementwise ----------------
__global__ void convert_f32_bf16(const float* __restrict__ in, ushort_t* __restrict__ outp, int n4) {
  int idx = blockIdx.x*256 + threadIdx.x;
  if (idx < n4) {
    float4v v = *reinterpret_cast<const float4v*>(in + (size_t)idx*4);
    ushort4v r;
    #pragma unroll
    for (int e=0;e<4;e++) r[e]=f2b(v[e]);
    *reinterpret_cast<ushort4v*>(outp + (size_t)idx*4) = r;
  }
}

// ---------------- fp32 [K][N] -> bf16 [N][K] transpose ----------------
__global__ void transpose_convert(const float* __restrict__ W, ushort_t* __restrict__ Wt, int K, int N) {
  __shared__ float tile[32][33];
  int nt = blockIdx.x, kt = blockIdx.y;
  int x = threadIdx.x, y = threadIdx.y;
  #pragma unroll
  for (int i=0;i<4;i++) {
    int k = kt*32 + y + i*8;
    tile[y+i*8][x] = W[(size_t)k*N + nt*32 + x];
  }
  __syncthreads();
  #pragma unroll
  for (int i=0;i<4;i++) {
    int n = nt*32 + y + i*8;
    Wt[(size_t)n*K + kt*32 + x] = f2b(tile[x][y+i*8]);
  }
}

// ---------------- bf16 [bh][T][HD] -> [bh][HD][T] transpose (for V) ----------------
__global__ void transpose_v(const ushort_t* __restrict__ Vin, ushort_t* __restrict__ Vout) {
  __shared__ ushort_t tile[32][34];
  int tt = blockIdx.x, dt = blockIdx.y, bh = blockIdx.z;
  int x = threadIdx.x, y = threadIdx.y;
  const ushort_t* src = Vin + (size_t)bh*T_*HD;
  ushort_t* dst = Vout + (size_t)bh*T_*HD;
  #pragma unroll
  for (int i=0;i<4;i++) {
    int t = tt*32 + y + i*8;
    tile[y+i*8][x] = src[(size_t)t*HD + dt*32 + x];
  }
  __syncthreads();
  #pragma unroll
  for (int i=0;i<4;i++) {
    int d = dt*32 + y + i*8;
    dst[(size_t)d*T_ + tt*32 + x] = tile[x][y+i*8];
  }
}

// ---------------- RoPE tables ----------------
__global__ void rope_tables(float* __restrict__ cosT, float* __restrict__ sinT) {
  int idx = blockIdx.x*256 + threadIdx.x;   // 2048*64
  int t = idx >> 6, i = idx & 63;
  float f = powf(10000.0f, -(float)(2*i)/128.0f);
  float ang = (float)t * f;
  cosT[idx] = cosf(ang);
  sinT[idx] = sinf(ang);
}

// ---------------- in-place RoPE on Q and K [BH][T][D] ----------------
__global__ void rope_apply(ushort_t* __restrict__ Q, ushort_t* __restrict__ K,
                           const float* __restrict__ cosT, const float* __restrict__ sinT) {
  int idx = blockIdx.x*256 + threadIdx.x;   // 64*2048*16
  int i4 = idx & 15;
  int t  = (idx >> 4) & (T_-1);
  int bh = idx >> 15;
  int d0 = i4*4;
  float4v c = *reinterpret_cast<const float4v*>(cosT + t*64 + d0);
  float4v s = *reinterpret_cast<const float4v*>(sinT + t*64 + d0);
  size_t p = ((size_t)bh*T_ + t)*HD;
  {
    ushort4v a = *reinterpret_cast<const ushort4v*>(Q + p + d0);
    ushort4v b = *reinterpret_cast<const ushort4v*>(Q + p + 64 + d0);
    ushort4v ra, rb;
    #pragma unroll
    for (int e=0;e<4;e++) {
      float x1=b2f(a[e]), x2=b2f(b[e]);
      ra[e]=f2b(x1*c[e]-x2*s[e]); rb[e]=f2b(x2*c[e]+x1*s[e]);
    }
    *reinterpret_cast<ushort4v*>(Q + p + d0) = ra;
    *reinterpret_cast<ushort4v*>(Q + p + 64 + d0) = rb;
  }
  {
    ushort4v a = *reinterpret_cast<const ushort4v*>(K + p + d0);
    ushort4v b = *reinterpret_cast<const ushort4v*>(K + p + 64 + d0);
    ushort4v ra, rb;
    #pragma unroll
    for (int e=0;e<4;e++) {
      float x1=b2f(a[e]), x2=b2f(b[e]);
      ra[e]=f2b(x1*c[e]-x2*s[e]); rb[e]=f2b(x2*c[e]+x1*s[e]);
    }
    *reinterpret_cast<ushort4v*>(K + p + d0) = ra;
    *reinterpret_cast<ushort4v*>(K + p + 64 + d0) = rb;
  }
}

// ---------------- GEMM: 256x256 tile, BK=64, 8 waves, 4-phase counted-vmcnt pipeline ---------
// A[M][K] bf16 x Bt[N][K] bf16. EPI 1: fp32 C[M][N]+bias; EPI 2: bias + scatter to Q/K/V.
// ds_reads issued BEFORE the pre-MFMA barrier (latency hides under barrier wait); vmcnt
// waits confirm data ONE PHASE AHEAD of its first read (race-free across wave skew).
template<int EPI>
__global__ __launch_bounds__(512, 2)
void gemm_kernel(const ushort_t* __restrict__ A, const ushort_t* __restrict__ Bt,
                 const float* __restrict__ bias, float* __restrict__ Cf,
                 ushort_t* __restrict__ Qb, ushort_t* __restrict__ Kb, ushort_t* __restrict__ Vb,
                 int M, int N, int K) {
  __shared__ __align__(16) ushort_t As[2][256*64];   // 64KB
  __shared__ __align__(16) ushort_t Bs[2][256*64];   // 64KB
  const int tid = threadIdx.x, lane = tid & 63, wid = tid >> 6;
  const int bm = blockIdx.x, bn = blockIdx.y;
  const int wr = wid >> 2, wc = wid & 3;      // 2M x 4N waves
  const int nt = K >> 6;

  f32x4 acc[2][2][4][2];
  #pragma unroll
  for (int a0=0;a0<2;a0++)
    #pragma unroll
    for (int a1=0;a1<2;a1++)
      #pragma unroll
      for (int a2=0;a2<4;a2++)
        #pragma unroll
        for (int a3=0;a3<2;a3++) { f32x4 z = {0.f,0.f,0.f,0.f}; acc[a0][a1][a2][a3] = z; }

  const ushort_t* Abase = A + (size_t)(bm*256)*K;
  const ushort_t* Bbase = Bt + (size_t)(bn*256)*K;

  // half-tiles: h=0 A rows 0-127, h=1 B rows 0-127, h=2 A rows 128-255, h=3 B rows 128-255
  auto stage_half = [&](int buf, int kt, int h) {
    const ushort_t* src = (h==0||h==2) ? Abase : Bbase;
    ushort_t* dst = (h==0||h==2) ? As[buf] : Bs[buf];
    const int rbase = (h>=2) ? 128 : 0;
    #pragma unroll
    for (int i=0;i<2;i++) {
      int c = i*512 + tid;            // 0..1023
      int row = rbase + (c>>3);
      int gl = (c&7) ^ (row&7);       // inverse-swizzled source, linear dest
      gload16(src + (size_t)row*K + kt*64 + gl*8, dst + rbase*64 + c*8);
    }
  };

  // prologue: stage tile 0 fully; confirm h0,h1 (oldest 4 of 8) before first reads
  stage_half(0,0,0); stage_half(0,0,1); stage_half(0,0,2); stage_half(0,0,3);
  asm volatile("s_waitcnt vmcnt(4)" ::: "memory");
  __builtin_amdgcn_sched_barrier(0);
  __builtin_amdgcn_s_barrier();
  __builtin_amdgcn_sched_barrier(0);

  bf16x8 af[4][2];   // A frags for current mh (reused across phases)
  bf16x8 bfr[2][2];  // B frags for current nh

  for (int kt=0; kt<nt; ++kt) {
    const int cur = kt & 1;
    const bool pf = (kt+1 < nt);
    // phase -> quadrant order: Q00, Q10, Q11, Q01  (A/B register reuse between neighbors)
    #pragma unroll
    for (int p=0;p<4;p++) {
      const int mh = (p==1||p==2) ? 1 : 0;
      const int nh = (p>=2) ? 1 : 0;
      if (pf) stage_half(cur^1, kt+1, p);
      // counted vmcnt, confirming the data needed ONE phase later:
      // steady: p0 -> kt.h2, p1 -> kt.h3, p3 -> (kt+1).h0/h1 ; all land at vmcnt(4).
      if (pf) {
        if (p!=2) asm volatile("s_waitcnt vmcnt(4)" ::: "memory");
      } else {
        if (p==0)      asm volatile("s_waitcnt vmcnt(2)" ::: "memory");
        else if (p==1) asm volatile("s_waitcnt vmcnt(0)" ::: "memory");
      }
      __builtin_amdgcn_sched_barrier(0);
      // ds_read THIS phase's fragments (data confirmed >= one barrier ago)
      if (p==0 || p==1 || p==3) {     // (re)load A frags for this mh
        #pragma unroll
        for (int mf=0;mf<4;mf++) {
          int r = mh*128 + wr*64 + mf*16 + (lane&15);
          #pragma unroll
          for (int ks=0;ks<2;ks++) {
            int gr = (ks*4 + (lane>>4)) ^ (r&7);
            af[mf][ks] = *reinterpret_cast<const bf16x8*>(&As[cur][r*64 + gr*8]);
          }
        }
      }
      if (p==0 || p==2) {             // (re)load B frags for this nh
        #pragma unroll
        for (int nf=0;nf<2;nf++) {
          int r = nh*128 + wc*32 + nf*16 + (lane&15);
          #pragma unroll
          for (int ks=0;ks<2;ks++) {
            int gr = (ks*4 + (lane>>4)) ^ (r&7);
            bfr[nf][ks] = *reinterpret_cast<const bf16x8*>(&Bs[cur][r*64 + gr*8]);
          }
        }
      }
      __builtin_amdgcn_sched_barrier(0);
      __builtin_amdgcn_s_barrier();
      __builtin_amdgcn_sched_barrier(0);
      __builtin_amdgcn_s_setprio(1);
      #pragma unroll
      for (int ks=0;ks<2;ks++)
        #pragma unroll
        for (int mf=0;mf<4;mf++)
          #pragma unroll
          for (int nf=0;nf<2;nf++)
            acc[mh][nh][mf][nf] = __builtin_amdgcn_mfma_f32_16x16x32_bf16(af[mf][ks], bfr[nf][ks], acc[mh][nh][mf][nf], 0,0,0);
      __builtin_amdgcn_s_setprio(0);
      __builtin_amdgcn_sched_barrier(0);
      __builtin_amdgcn_s_barrier();
      __builtin_amdgcn_sched_barrier(0);
    }
  }

  #pragma unroll
  for (int mh=0;mh<2;mh++)
    #pragma unroll
    for (int nh=0;nh<2;nh++)
      #pragma unroll
      for (int mf=0;mf<4;mf++)
        #pragma unroll
        for (int j=0;j<4;j++) {
          int row = bm*256 + mh*128 + wr*64 + mf*16 + (lane>>4)*4 + j;
          #pragma unroll
          for (int nf=0;nf<2;nf++) {
            int col = bn*256 + nh*128 + wc*32 + nf*16 + (lane&15);
            float v = acc[mh][nh][mf][nf][j] + bias[col];
            if (EPI == 1) {
              Cf[(size_t)row*N + col] = v;
            } else {
              int which = col >> 11, hh = (col>>7)&15, d = col&127;
              int bb = row >> 11, t = row & (T_-1);
              ushort_t* dst = which==0 ? Qb : (which==1 ? Kb : Vb);
              dst[(((size_t)(bb*NH + hh))*T_ + t)*HD + d] = f2b(v);
            }
          }
        }
}

// ---------------- flash attention ----------------
// Q,K [BH][T][D]; Vt [BH][D][T]; Y [B,T,C] bf16. QBLK=128 (8 waves x 16 rows), KVBLK=64.
// Swapped-operand MFMA: each lane owns ONE q-row (q = lane&15) -> in-lane softmax,
// only 2 shuffles per reduce. Double-buffered K/V staging, counted vmcnt.
__device__ __forceinline__ int psw(int row, int col){ return (row*64 + col) ^ ((row&7)<<3); }

__global__ __launch_bounds__(512, 4)
void attn_kernel(const ushort_t* __restrict__ Q, const ushort_t* __restrict__ K,
                 const ushort_t* __restrict__ Vt, ushort_t* __restrict__ Y) {
  __shared__ __align__(16) ushort_t Ks[2][64*128];   // 32KB
  __shared__ __align__(16) ushort_t Vs[2][128*64];   // 32KB (V^T rows: d, t-contiguous)
  __shared__ __align__(16) ushort_t Ps[128*64];      // 16KB, XOR-swizzled
  const int tid = threadIdx.x, lane = tid & 63, w = tid >> 6;
  const int qtb = (int)gridDim.x - 1 - (int)blockIdx.x;   // heavy blocks first
  const int bh = blockIdx.y;
  const size_t base = (size_t)bh * T_ * HD;

  const int NT = 2*qtb + 2;
  const int qmin = qtb*128 + w*16;
  const int qrow = qmin + (lane&15);      // this lane's q row (swapped layout)

  auto stage = [&](int buf, int kvt) {
    #pragma unroll
    for (int i=0;i<2;i++) {
      int c = i*512 + tid;
      int row = c >> 4, g = c & 15;
      int gl = (g & 8) | ((g ^ row) & 7);
      gload16(K + base + (size_t)(kvt*64 + row)*HD + gl*8, &Ks[buf][c*8]);
    }
    #pragma unroll
    for (int i=0;i<2;i++) {
      int c = i*512 + tid;
      int d = c >> 3, g = c & 7;
      int gl = g ^ (d & 7);
      gload16(Vt + base + (size_t)d*T_ + kvt*64 + gl*8, &Vs[buf][c*8]);
    }
  };

  stage(0, 0);

  bf16x8 qf[4];
  {
    const ushort_t* qp = Q + base + (size_t)qrow*HD + (lane>>4)*8;
    #pragma unroll
    for (int ks=0; ks<4; ++ks) qf[ks] = *reinterpret_cast<const bf16x8*>(qp + ks*32);
  }

  f32x4 o[8];
  #pragma unroll
  for (int i=0;i<8;i++) { f32x4 z = {0.f,0.f,0.f,0.f}; o[i] = z; }
  float mi = -1e30f, li = 0.f;
  const float C_ = 0.088388347648318447f * 1.4426950408889634f; // scale*log2e

  for (int kvt=0; kvt<NT; ++kvt) {
    int cur = kvt & 1;
    if (kvt+1 < NT) {
      stage(cur^1, kvt+1);
      asm volatile("s_waitcnt vmcnt(4)" ::: "memory");   // tile kvt's loads landed
    } else {
      asm volatile("s_waitcnt vmcnt(0)" ::: "memory");
    }
    __builtin_amdgcn_sched_barrier(0);
    __builtin_amdgcn_s_barrier();
    __builtin_amdgcn_sched_barrier(0);

    bool active = (kvt*64 <= qmin + 15);
    if (active) {
      f32x4 s[4];
      #pragma unroll
      for (int nb=0;nb<4;nb++) { f32x4 z = {0.f,0.f,0.f,0.f}; s[nb] = z; }
      __builtin_amdgcn_s_setprio(1);
      #pragma unroll
      for (int ks=0;ks<4;ks++) {
        #pragma unroll
        for (int nb=0;nb<4;nb++) {
          int r = nb*16 + (lane&15);
          int gr = ks*4 + (lane>>4);
          int gl = (gr & 8) | ((gr ^ r) & 7);
          bf16x8 kf = *reinterpret_cast<const bf16x8*>(&Ks[cur][r*128 + gl*8]);
          s[nb] = __builtin_amdgcn_mfma_f32_16x16x32_bf16(kf, qf[ks], s[nb], 0,0,0);  // S^T
        }
      }
      __builtin_amdgcn_s_setprio(0);
      bool diag = (kvt*64 + 63 > qmin);
      if (diag) {
        #pragma unroll
        for (int nb=0;nb<4;nb++) {
          int kvb = kvt*64 + nb*16 + (lane>>4)*4;
          #pragma unroll
          for (int j=0;j<4;j++)
            if (kvb + j > qrow) s[nb][j] = -1e30f;
        }
      }
      // in-lane max tree over 16 values, then 2 shuffles
      float t0 = fmaxf(fmaxf(s[0][0],s[0][1]), fmaxf(s[0][2],s[0][3]));
      float t1 = fmaxf(fmaxf(s[1][0],s[1][1]), fmaxf(s[1][2],s[1][3]));
      float t2 = fmaxf(fmaxf(s[2][0],s[2][1]), fmaxf(s[2][2],s[2][3]));
      float t3 = fmaxf(fmaxf(s[3][0],s[3][1]), fmaxf(s[3][2],s[3][3]));
      float pm = fmaxf(fmaxf(t0,t1), fmaxf(t2,t3));
      pm = fmaxf(pm, __shfl_xor(pm, 16));
      pm = fmaxf(pm, __shfl_xor(pm, 32));
      float mn = fmaxf(mi, pm);
      float alpha = fexp2((mi - mn)*C_);
      mi = mn;
      // p = exp2((s-mn)*C), packed LDS write (4 contiguous kv per nb)
      float p[4][4];
      #pragma unroll
      for (int nb=0;nb<4;nb++) {
        ushort4v pw;
        #pragma unroll
        for (int j=0;j<4;j++) {
          p[nb][j] = fexp2((s[nb][j] - mn)*C_);
          pw[j] = f2b(p[nb][j]);
        }
        *reinterpret_cast<ushort4v*>(&Ps[psw(w*16 + (lane&15), nb*16 + (lane>>4)*4)]) = pw;
      }
      // in-lane sum tree + 2 shuffles
      float r0 = (p[0][0]+p[0][1]) + (p[0][2]+p[0][3]);
      float r1 = (p[1][0]+p[1][1]) + (p[1][2]+p[1][3]);
      float r2 = (p[2][0]+p[2][1]) + (p[2][2]+p[2][3]);
      float r3 = (p[3][0]+p[3][1]) + (p[3][2]+p[3][3]);
      float rs = (r0+r1) + (r2+r3);
      rs += __shfl_xor(rs, 16);
      rs += __shfl_xor(rs, 32);
      li = li*alpha + rs;
      #pragma unroll
      for (int i=0;i<8;i++)
        #pragma unroll
        for (int j=0;j<4;j++) o[i][j] *= alpha;
      __builtin_amdgcn_s_setprio(1);
      #pragma unroll
      for (int ks2=0; ks2<2; ++ks2) {
        bf16x8 pa = *reinterpret_cast<const bf16x8*>(&Ps[psw(w*16 + (lane&15), ks2*32 + (lane>>4)*8)]);
        #pragma unroll
        for (int nb2=0; nb2<8; ++nb2) {
          int d = nb2*16 + (lane&15);
          int gc = ks2*4 + (lane>>4);
          int gl = gc ^ (d & 7);
          bf16x8 vb = *reinterpret_cast<const bf16x8*>(&Vs[cur][d*64 + gl*8]);
          o[nb2] = __builtin_amdgcn_mfma_f32_16x16x32_bf16(vb, pa, o[nb2], 0,0,0);  // (PV)^T
        }
      }
      __builtin_amdgcn_s_setprio(0);
    }
    __builtin_amdgcn_s_barrier();            // all readers done before next stage overwrites
    __builtin_amdgcn_sched_barrier(0);
  }

  // epilogue: lane owns q=qrow; o[nb2][j] = Y[qrow][nb2*16 + (lane>>4)*4 + j]
  int bb = bh >> 4, h = bh & 15;
  float inv = 1.0f / li;
  size_t rowbase = ((size_t)(bb*T_ + qrow))*D_MODEL + h*HD;
  #pragma unroll
  for (int nb2=0;nb2<8;nb2++) {
    ushort4v r;
    #pragma unroll
    for (int j=0;j<4;j++) r[j] = f2b(o[nb2][j] * inv);
    *reinterpret_cast<ushort4v*>(&Y[rowbase + nb2*16 + (lane>>4)*4]) = r;
  }
}

extern "C" void kernel_launch(void* const* d_in, const int* in_sizes, int n_in,
                              void* d_out, int out_size, void* d_ws, size_t ws_size,
                              hipStream_t stream) {
  const float* x      = (const float*)d_in[0];
  const float* W_attn = (const float*)d_in[1];
  const float* b_attn = (const float*)d_in[2];
  const float* W_proj = (const float*)d_in[3];
  const float* b_proj = (const float*)d_in[4];
  float* out = (float*)d_out;

  char* ws = (char*)d_ws;
  size_t off = 0;
  ushort_t* xb = (ushort_t*)(ws + off); off += (size_t)M_*D_MODEL*2;        // 33.5MB
  ushort_t* Wa = (ushort_t*)(ws + off); off += (size_t)3*D_MODEL*D_MODEL*2; // 25.2MB
  ushort_t* Wp = (ushort_t*)(ws + off); off += (size_t)D_MODEL*D_MODEL*2;   // 8.4MB
  ushort_t* Qb = (ushort_t*)(ws + off); off += (size_t)M_*D_MODEL*2;        // 33.5MB
  ushort_t* Kb = (ushort_t*)(ws + off); off += (size_t)M_*D_MODEL*2;        // 33.5MB
  ushort_t* Vb = (ushort_t*)(ws + off); off += (size_t)M_*D_MODEL*2;        // 33.5MB
  ushort_t* Vtg= (ushort_t*)(ws + off); off += (size_t)M_*D_MODEL*2;        // 33.5MB
  float* cosT = (float*)(ws + off); off += (size_t)T_*64*4;                 // 0.5MB
  float* sinT = (float*)(ws + off); off += (size_t)T_*64*4;                 // 0.5MB
  ushort_t* Yatt = xb;  // alias: xb dead after GEMM1

  convert_f32_bf16<<<16384, 256, 0, stream>>>(x, xb, M_*D_MODEL/4);
  transpose_convert<<<dim3(192,64), dim3(32,8), 0, stream>>>(W_attn, Wa, D_MODEL, 3*D_MODEL);
  transpose_convert<<<dim3(64,64), dim3(32,8), 0, stream>>>(W_proj, Wp, D_MODEL, D_MODEL);
  rope_tables<<<512, 256, 0, stream>>>(cosT, sinT);

  gemm_kernel<2><<<dim3(32,24), 512, 0, stream>>>(xb, Wa, b_attn, nullptr,
                                                  Qb, Kb, Vb, M_, 3*D_MODEL, D_MODEL);
  rope_apply<<<8192, 256, 0, stream>>>(Qb, Kb, cosT, sinT);
  transpose_v<<<dim3(64,4,64), dim3(32,8), 0, stream>>>(Vb, Vtg);
  attn_kernel<<<dim3(16,64), 512, 0, stream>>>(Qb, Kb, Vtg, Yatt);
  gemm_kernel<1><<<dim3(32,8), 512, 0, stream>>>(Yatt, Wp, b_proj, out,
                                                 nullptr, nullptr, nullptr, M_, D_MODEL, D_MODEL);
}

// Round 8
// 546.117 us; speedup vs baseline: 1.0970x; 1.0970x over previous
//
#include <hip/hip_runtime.h>
#include <hip/hip_bf16.h>
#include <stdint.h>

typedef __bf16 bf16x8 __attribute__((ext_vector_type(8)));
typedef float f32x4 __attribute__((ext_vector_type(4)));
typedef unsigned short ushort_t;
typedef ushort_t ushort4v __attribute__((ext_vector_type(4)));
typedef ushort_t ushort8v __attribute__((ext_vector_type(8)));
typedef float float4v __attribute__((ext_vector_type(4)));

#define D_MODEL 2048
#define NH 16
#define HD 128
#define B_ 4
#define T_ 2048
#define M_ (B_*T_)

__device__ __forceinline__ float b2f(ushort_t u){ union{uint32_t i; float f;} v; v.i=((uint32_t)u)<<16; return v.f; }
__device__ __forceinline__ ushort_t f2b(float f){ union{float f; uint32_t i;} v; v.f=f; uint32_t r = v.i + 0x7FFFu + ((v.i>>16)&1u); return (ushort_t)(r>>16); }
__device__ __forceinline__ float fexp2(float x){ return __builtin_amdgcn_exp2f(x); }

__device__ __forceinline__ void gload16(const void* g, void* l) {
  __builtin_amdgcn_global_load_lds((const __attribute__((address_space(1))) void*)g,
                                   (__attribute__((address_space(3))) void*)l, 16, 0, 0);
}

// ---------------- fp32 -> bf16 elementwise ----------------
__global__ void convert_f32_bf16(const float* __restrict__ in, ushort_t* __restrict__ outp, int n4) {
  int idx = blockIdx.x*256 + threadIdx.x;
  if (idx < n4) {
    float4v v = *reinterpret_cast<const float4v*>(in + (size_t)idx*4);
    ushort4v r;
    #pragma unroll
    for (int e=0;e<4;e++) r[e]=f2b(v[e]);
    *reinterpret_cast<ushort4v*>(outp + (size_t)idx*4) = r;
  }
}

// ---------------- fp32 [K][N] -> bf16 [N][K] transpose ----------------
__global__ void transpose_convert(const float* __restrict__ W, ushort_t* __restrict__ Wt, int K, int N) {
  __shared__ float tile[32][33];
  int nt = blockIdx.x, kt = blockIdx.y;
  int x = threadIdx.x, y = threadIdx.y;
  #pragma unroll
  for (int i=0;i<4;i++) {
    int k = kt*32 + y + i*8;
    tile[y+i*8][x] = W[(size_t)k*N + nt*32 + x];
  }
  __syncthreads();
  #pragma unroll
  for (int i=0;i<4;i++) {
    int n = nt*32 + y + i*8;
    Wt[(size_t)n*K + kt*32 + x] = f2b(tile[x][y+i*8]);
  }
}

// ---------------- RoPE tables ----------------
__global__ void rope_tables(float* __restrict__ cosT, float* __restrict__ sinT) {
  int idx = blockIdx.x*256 + threadIdx.x;   // 2048*64
  int t = idx >> 6, i = idx & 63;
  float f = powf(10000.0f, -(float)(2*i)/128.0f);
  float ang = (float)t * f;
  cosT[idx] = cosf(ang);
  sinT[idx] = sinf(ang);
}

// ---------------- GEMM: 128x128 tile, BK=64, 4 waves (R5 proven structure) ----------------
// A[M][K] bf16 x Bt[N][K] bf16.
// EPI 1: fp32 C[M][N] + bias (proj output).
// EPI 2: QKV fused epilogue: bias + (Q,K: RoPE applied, coalesced [bh][t][d] write) or
//        (V: transposed write to Vt [bh][d][t]). Each 128-col tile = exactly one head.
template<int EPI>
__global__ __launch_bounds__(256, 2)
void gemm_kernel(const ushort_t* __restrict__ A, const ushort_t* __restrict__ Bt,
                 const float* __restrict__ bias, float* __restrict__ Cf,
                 ushort_t* __restrict__ Qb, ushort_t* __restrict__ Kb, ushort_t* __restrict__ Vb,
                 const float* __restrict__ cosT, const float* __restrict__ sinT,
                 int M, int N, int K) {
  __shared__ __align__(16) ushort_t As[2][128*64];
  __shared__ __align__(16) ushort_t Bs[2][128*64];
  const int tid = threadIdx.x, lane = tid & 63, wid = tid >> 6;
  const int bm = blockIdx.x, bn = blockIdx.y;
  const int wr = wid >> 1, wc = wid & 1;
  const int nt = K >> 6;

  f32x4 acc[4][4];
  #pragma unroll
  for (int m=0;m<4;m++)
    #pragma unroll
    for (int n=0;n<4;n++) { f32x4 z = {0.f,0.f,0.f,0.f}; acc[m][n] = z; }

  const ushort_t* Abase = A + (size_t)(bm*128)*K;
  const ushort_t* Bbase = Bt + (size_t)(bn*128)*K;

  auto stage = [&](int buf, int kt) {
    const int rsub = (lane>>3);
    const int g = lane & 7;
    #pragma unroll
    for (int i=0;i<4;i++) {
      int chunk = wid*4 + i;
      int row = chunk*8 + rsub;
      int gl = g ^ (row & 7);
      gload16(Abase + (size_t)row*K + kt*64 + gl*8, &As[buf][chunk*512 + lane*8]);
      gload16(Bbase + (size_t)row*K + kt*64 + gl*8, &Bs[buf][chunk*512 + lane*8]);
    }
  };

  stage(0, 0);
  __syncthreads();

  for (int kt=0; kt<nt; ++kt) {
    int cur = kt & 1;
    if (kt+1 < nt) stage(cur^1, kt+1);
    #pragma unroll
    for (int ks=0; ks<2; ++ks) {
      bf16x8 a[4], b[4];
      #pragma unroll
      for (int m=0;m<4;m++) {
        int r = wr*64 + m*16 + (lane&15);
        int gr = (ks*4 + (lane>>4)) ^ (r&7);
        a[m] = *reinterpret_cast<const bf16x8*>(&As[cur][r*64 + gr*8]);
      }
      #pragma unroll
      for (int n=0;n<4;n++) {
        int r = wc*64 + n*16 + (lane&15);
        int gr = (ks*4 + (lane>>4)) ^ (r&7);
        b[n] = *reinterpret_cast<const bf16x8*>(&Bs[cur][r*64 + gr*8]);
      }
      #pragma unroll
      for (int m=0;m<4;m++)
        #pragma unroll
        for (int n=0;n<4;n++)
          acc[m][n] = __builtin_amdgcn_mfma_f32_16x16x32_bf16(a[m], b[n], acc[m][n], 0,0,0);
    }
    __syncthreads();
  }

  if (EPI == 1) {
    #pragma unroll
    for (int m=0;m<4;m++)
      #pragma unroll
      for (int j=0;j<4;j++) {
        int row = bm*128 + wr*64 + m*16 + (lane>>4)*4 + j;
        #pragma unroll
        for (int n=0;n<4;n++) {
          int col = bn*128 + wc*64 + n*16 + (lane&15);
          Cf[(size_t)row*N + col] = acc[m][n][j] + bias[col];
        }
      }
  } else {
    // ---- fused QKV epilogue ----
    ushort_t* sc = &As[0][0];                 // 32KB scratch (As dead after K loop)
    const int which = bn >> 4;                // 0=Q, 1=K, 2=V
    const int h = bn & 15;
    if (which < 2) {
      // row-major swizzled store: ushort idx = r*128 + ((c>>3)^(r&15))*8 + (c&7)
      #pragma unroll
      for (int m=0;m<4;m++)
        #pragma unroll
        for (int j=0;j<4;j++) {
          int r = wr*64 + m*16 + (lane>>4)*4 + j;
          #pragma unroll
          for (int n=0;n<4;n++) {
            int c = wc*64 + n*16 + (lane&15);
            float v = acc[m][n][j] + bias[bn*128 + c];
            sc[r*128 + ((((c>>3)^(r&15)))<<3) + (c&7)] = f2b(v);
          }
        }
    } else {
      // transposed swizzled store: idx = c*128 + ((r>>3)^(c&15))*8 + (r&7)
      #pragma unroll
      for (int m=0;m<4;m++)
        #pragma unroll
        for (int j=0;j<4;j++) {
          int r = wr*64 + m*16 + (lane>>4)*4 + j;
          #pragma unroll
          for (int n=0;n<4;n++) {
            int c = wc*64 + n*16 + (lane&15);
            float v = acc[m][n][j] + bias[bn*128 + c];
            sc[c*128 + ((((r>>3)^(c&15)))<<3) + (r&7)] = f2b(v);
          }
        }
    }
    __syncthreads();
    if (which < 2) {
      ushort_t* dst = (which==0) ? Qb : Kb;
      int r = tid >> 1, hp = tid & 1;
      int t = bm*128 + r;
      int bb = t >> 11, tt = t & (T_-1);
      float lo[32], hi[32];
      #pragma unroll
      for (int k=0;k<4;k++) {
        ushort8v u = *reinterpret_cast<const ushort8v*>(&sc[r*128 + (((hp*4+k)^(r&15))<<3)]);
        #pragma unroll
        for (int e=0;e<8;e++) lo[k*8+e] = b2f(u[e]);
      }
      #pragma unroll
      for (int k=0;k<4;k++) {
        ushort8v u = *reinterpret_cast<const ushort8v*>(&sc[r*128 + (((8+hp*4+k)^(r&15))<<3)]);
        #pragma unroll
        for (int e=0;e<8;e++) hi[k*8+e] = b2f(u[e]);
      }
      ushort_t* basep = dst + (((size_t)(bb*NH + h))*T_ + tt)*HD + hp*32;
      const float* cp = cosT + tt*64 + hp*32;
      const float* sp = sinT + tt*64 + hp*32;
      #pragma unroll
      for (int k=0;k<4;k++) {
        ushort8v rlo, rhi;
        #pragma unroll
        for (int e=0;e<8;e++) {
          float cd = cp[k*8+e], sd = sp[k*8+e];
          float x1 = lo[k*8+e], x2 = hi[k*8+e];
          rlo[e] = f2b(x1*cd - x2*sd);
          rhi[e] = f2b(x2*cd + x1*sd);
        }
        *reinterpret_cast<ushort8v*>(basep + k*8) = rlo;
        *reinterpret_cast<ushort8v*>(basep + 64 + k*8) = rhi;
      }
    } else {
      int dr = tid >> 1, th = tid & 1;
      int bb = bm >> 4;
      int t0 = (bm & 15)*128 + th*64;
      ushort_t* dstp = Vb + (((size_t)(bb*NH + h))*HD + dr)*T_ + t0;
      #pragma unroll
      for (int k=0;k<8;k++) {
        ushort8v u = *reinterpret_cast<const ushort8v*>(&sc[dr*128 + (((th*8+k)^(dr&15))<<3)]);
        *reinterpret_cast<ushort8v*>(dstp + k*8) = u;
      }
    }
  }
}

// ---------------- flash attention ----------------
// Q,K [BH][T][D]; Vt [BH][D][T]; Y [B,T,C] bf16. QBLK=128 (8 waves x 16 rows), KVBLK=64.
// Swapped-operand MFMA: each lane owns ONE q-row (q = lane&15) -> in-lane softmax,
// only 2 shuffles per reduce. Double-buffered K/V staging, counted vmcnt.
__device__ __forceinline__ int psw(int row, int col){ return (row*64 + col) ^ ((row&7)<<3); }

__global__ __launch_bounds__(512, 4)
void attn_kernel(const ushort_t* __restrict__ Q, const ushort_t* __restrict__ K,
                 const ushort_t* __restrict__ Vt, ushort_t* __restrict__ Y) {
  __shared__ __align__(16) ushort_t Ks[2][64*128];   // 32KB
  __shared__ __align__(16) ushort_t Vs[2][128*64];   // 32KB (V^T rows: d, t-contiguous)
  __shared__ __align__(16) ushort_t Ps[128*64];      // 16KB, XOR-swizzled
  const int tid = threadIdx.x, lane = tid & 63, w = tid >> 6;
  const int qtb = (int)gridDim.x - 1 - (int)blockIdx.x;   // heavy blocks first
  const int bh = blockIdx.y;
  const size_t base = (size_t)bh * T_ * HD;

  const int NT = 2*qtb + 2;
  const int qmin = qtb*128 + w*16;
  const int qrow = qmin + (lane&15);      // this lane's q row (swapped layout)

  auto stage = [&](int buf, int kvt) {
    #pragma unroll
    for (int i=0;i<2;i++) {
      int c = i*512 + tid;
      int row = c >> 4, g = c & 15;
      int gl = (g & 8) | ((g ^ row) & 7);
      gload16(K + base + (size_t)(kvt*64 + row)*HD + gl*8, &Ks[buf][c*8]);
    }
    #pragma unroll
    for (int i=0;i<2;i++) {
      int c = i*512 + tid;
      int d = c >> 3, g = c & 7;
      int gl = g ^ (d & 7);
      gload16(Vt + base + (size_t)d*T_ + kvt*64 + gl*8, &Vs[buf][c*8]);
    }
  };

  stage(0, 0);

  bf16x8 qf[4];
  {
    const ushort_t* qp = Q + base + (size_t)qrow*HD + (lane>>4)*8;
    #pragma unroll
    for (int ks=0; ks<4; ++ks) qf[ks] = *reinterpret_cast<const bf16x8*>(qp + ks*32);
  }

  f32x4 o[8];
  #pragma unroll
  for (int i=0;i<8;i++) { f32x4 z = {0.f,0.f,0.f,0.f}; o[i] = z; }
  float mi = -1e30f, li = 0.f;
  const float C_ = 0.088388347648318447f * 1.4426950408889634f; // scale*log2e

  for (int kvt=0; kvt<NT; ++kvt) {
    int cur = kvt & 1;
    if (kvt+1 < NT) {
      stage(cur^1, kvt+1);
      asm volatile("s_waitcnt vmcnt(4)" ::: "memory");   // tile kvt's loads landed
    } else {
      asm volatile("s_waitcnt vmcnt(0)" ::: "memory");
    }
    __builtin_amdgcn_sched_barrier(0);
    __builtin_amdgcn_s_barrier();
    __builtin_amdgcn_sched_barrier(0);

    bool active = (kvt*64 <= qmin + 15);
    if (active) {
      f32x4 s[4];
      #pragma unroll
      for (int nb=0;nb<4;nb++) { f32x4 z = {0.f,0.f,0.f,0.f}; s[nb] = z; }
      __builtin_amdgcn_s_setprio(1);
      #pragma unroll
      for (int ks=0;ks<4;ks++) {
        #pragma unroll
        for (int nb=0;nb<4;nb++) {
          int r = nb*16 + (lane&15);
          int gr = ks*4 + (lane>>4);
          int gl = (gr & 8) | ((gr ^ r) & 7);
          bf16x8 kf = *reinterpret_cast<const bf16x8*>(&Ks[cur][r*128 + gl*8]);
          s[nb] = __builtin_amdgcn_mfma_f32_16x16x32_bf16(kf, qf[ks], s[nb], 0,0,0);  // S^T
        }
      }
      __builtin_amdgcn_s_setprio(0);
      bool diag = (kvt*64 + 63 > qmin);
      if (diag) {
        #pragma unroll
        for (int nb=0;nb<4;nb++) {
          int kvb = kvt*64 + nb*16 + (lane>>4)*4;
          #pragma unroll
          for (int j=0;j<4;j++)
            if (kvb + j > qrow) s[nb][j] = -1e30f;
        }
      }
      // in-lane max tree over 16 values, then 2 shuffles
      float t0 = fmaxf(fmaxf(s[0][0],s[0][1]), fmaxf(s[0][2],s[0][3]));
      float t1 = fmaxf(fmaxf(s[1][0],s[1][1]), fmaxf(s[1][2],s[1][3]));
      float t2 = fmaxf(fmaxf(s[2][0],s[2][1]), fmaxf(s[2][2],s[2][3]));
      float t3 = fmaxf(fmaxf(s[3][0],s[3][1]), fmaxf(s[3][2],s[3][3]));
      float pm = fmaxf(fmaxf(t0,t1), fmaxf(t2,t3));
      pm = fmaxf(pm, __shfl_xor(pm, 16));
      pm = fmaxf(pm, __shfl_xor(pm, 32));
      float mn = fmaxf(mi, pm);
      float alpha = fexp2((mi - mn)*C_);
      mi = mn;
      // p = exp2((s-mn)*C), packed LDS write (4 contiguous kv per nb)
      float p[4][4];
      #pragma unroll
      for (int nb=0;nb<4;nb++) {
        ushort4v pw;
        #pragma unroll
        for (int j=0;j<4;j++) {
          p[nb][j] = fexp2((s[nb][j] - mn)*C_);
          pw[j] = f2b(p[nb][j]);
        }
        *reinterpret_cast<ushort4v*>(&Ps[psw(w*16 + (lane&15), nb*16 + (lane>>4)*4)]) = pw;
      }
      // in-lane sum tree + 2 shuffles
      float r0 = (p[0][0]+p[0][1]) + (p[0][2]+p[0][3]);
      float r1 = (p[1][0]+p[1][1]) + (p[1][2]+p[1][3]);
      float r2 = (p[2][0]+p[2][1]) + (p[2][2]+p[2][3]);
      float r3 = (p[3][0]+p[3][1]) + (p[3][2]+p[3][3]);
      float rs = (r0+r1) + (r2+r3);
      rs += __shfl_xor(rs, 16);
      rs += __shfl_xor(rs, 32);
      li = li*alpha + rs;
      #pragma unroll
      for (int i=0;i<8;i++)
        #pragma unroll
        for (int j=0;j<4;j++) o[i][j] *= alpha;
      __builtin_amdgcn_s_setprio(1);
      #pragma unroll
      for (int ks2=0; ks2<2; ++ks2) {
        bf16x8 pa = *reinterpret_cast<const bf16x8*>(&Ps[psw(w*16 + (lane&15), ks2*32 + (lane>>4)*8)]);
        #pragma unroll
        for (int nb2=0; nb2<8; ++nb2) {
          int d = nb2*16 + (lane&15);
          int gc = ks2*4 + (lane>>4);
          int gl = gc ^ (d & 7);
          bf16x8 vb = *reinterpret_cast<const bf16x8*>(&Vs[cur][d*64 + gl*8]);
          o[nb2] = __builtin_amdgcn_mfma_f32_16x16x32_bf16(vb, pa, o[nb2], 0,0,0);  // (PV)^T
        }
      }
      __builtin_amdgcn_s_setprio(0);
    }
    __builtin_amdgcn_s_barrier();            // all readers done before next stage overwrites
    __builtin_amdgcn_sched_barrier(0);
  }

  // epilogue: lane owns q=qrow; o[nb2][j] = Y[qrow][nb2*16 + (lane>>4)*4 + j]
  int bb = bh >> 4, h = bh & 15;
  float inv = 1.0f / li;
  size_t rowbase = ((size_t)(bb*T_ + qrow))*D_MODEL + h*HD;
  #pragma unroll
  for (int nb2=0;nb2<8;nb2++) {
    ushort4v r;
    #pragma unroll
    for (int j=0;j<4;j++) r[j] = f2b(o[nb2][j] * inv);
    *reinterpret_cast<ushort4v*>(&Y[rowbase + nb2*16 + (lane>>4)*4]) = r;
  }
}

extern "C" void kernel_launch(void* const* d_in, const int* in_sizes, int n_in,
                              void* d_out, int out_size, void* d_ws, size_t ws_size,
                              hipStream_t stream) {
  const float* x      = (const float*)d_in[0];
  const float* W_attn = (const float*)d_in[1];
  const float* b_attn = (const float*)d_in[2];
  const float* W_proj = (const float*)d_in[3];
  const float* b_proj = (const float*)d_in[4];
  float* out = (float*)d_out;

  char* ws = (char*)d_ws;
  size_t off = 0;
  ushort_t* xb = (ushort_t*)(ws + off); off += (size_t)M_*D_MODEL*2;        // 33.5MB
  ushort_t* Wa = (ushort_t*)(ws + off); off += (size_t)3*D_MODEL*D_MODEL*2; // 25.2MB
  ushort_t* Wp = (ushort_t*)(ws + off); off += (size_t)D_MODEL*D_MODEL*2;   // 8.4MB
  ushort_t* Qb = (ushort_t*)(ws + off); off += (size_t)M_*D_MODEL*2;        // 33.5MB
  ushort_t* Kb = (ushort_t*)(ws + off); off += (size_t)M_*D_MODEL*2;        // 33.5MB
  ushort_t* Vtg= (ushort_t*)(ws + off); off += (size_t)M_*D_MODEL*2;        // 33.5MB
  float* cosT = (float*)(ws + off); off += (size_t)T_*64*4;                 // 0.5MB
  float* sinT = (float*)(ws + off); off += (size_t)T_*64*4;                 // 0.5MB
  ushort_t* Yatt = xb;  // alias: xb dead after GEMM1

  convert_f32_bf16<<<16384, 256, 0, stream>>>(x, xb, M_*D_MODEL/4);
  transpose_convert<<<dim3(192,64), dim3(32,8), 0, stream>>>(W_attn, Wa, D_MODEL, 3*D_MODEL);
  transpose_convert<<<dim3(64,64), dim3(32,8), 0, stream>>>(W_proj, Wp, D_MODEL, D_MODEL);
  rope_tables<<<512, 256, 0, stream>>>(cosT, sinT);

  gemm_kernel<2><<<dim3(64,48), 256, 0, stream>>>(xb, Wa, b_attn, nullptr,
                                                  Qb, Kb, Vtg, cosT, sinT, M_, 3*D_MODEL, D_MODEL);
  attn_kernel<<<dim3(16,64), 512, 0, stream>>>(Qb, Kb, Vtg, Yatt);
  gemm_kernel<1><<<dim3(64,16), 256, 0, stream>>>(Yatt, Wp, b_proj, out,
                                                  nullptr, nullptr, nullptr, nullptr, nullptr,
                                                  M_, D_MODEL, D_MODEL);
}